// Round 13
// baseline (38.199 us; speedup 1.0000x reference)
//
#include <hip/hip_runtime.h>
#include <math.h>

#define B_     32
#define S_     1024
#define H2_    1024
#define TOPIC_ 256

typedef float f4 __attribute__((ext_vector_type(4)));

__device__ __forceinline__ float fast_tanh(float x) {
    // tanh(x) = 1 - 2/(exp(2x)+1); saturates to +-1 at extremes.
    float e = __expf(2.0f * x);
    return 1.0f - 2.0f / (e + 1.0f);
}

// Kernel 1: combined[b][h] = sum_k s[b][k]*W_s[k][h] + sum_j hz[b][j]*W_z[j][h] + b_c[h]
// grid = (H2/32, B) = (32, 32), block = 256 (8 k-chunks x 32 h).
// 16 independent accumulators: 160 loads/thread -> 10 dependent load rounds.
__global__ __launch_bounds__(256) void combined_kernel(
    const float* __restrict__ s,    // [B, H2]
    const float* __restrict__ hz,   // [B, TOPIC]
    const float* __restrict__ W_s,  // [H2, H2]  (in, out)
    const float* __restrict__ W_z,  // [TOPIC, H2]
    const float* __restrict__ b_c,  // [H2]
    float* __restrict__ combined)   // [B, H2]
{
    const int b  = blockIdx.y;
    const int hl = threadIdx.x & 31;
    const int h  = blockIdx.x * 32 + hl;
    const int kc = threadIdx.x >> 5;   // 0..7

    __shared__ float sx[H2_];
    __shared__ float zx[TOPIC_];
    for (int i = threadIdx.x; i < H2_; i += 256)    sx[i] = s[b * H2_ + i];
    for (int i = threadIdx.x; i < TOPIC_; i += 256) zx[i] = hz[b * TOPIC_ + i];
    __syncthreads();

    float a[16];
    #pragma unroll
    for (int u = 0; u < 16; ++u) a[u] = 0.0f;
    {
        const int k0 = kc * 128;                       // 1024 / 8
        const float* Wp = W_s + (size_t)k0 * H2_ + h;
        #pragma unroll
        for (int i = 0; i < 128; i += 16) {
            #pragma unroll
            for (int u = 0; u < 16; ++u)
                a[u] = fmaf(sx[k0 + i + u], Wp[(size_t)(i + u) * H2_], a[u]);
        }
    }
    {
        const int j0 = kc * 32;                        // 256 / 8
        const float* Wp = W_z + (size_t)j0 * H2_ + h;
        #pragma unroll
        for (int i = 0; i < 32; i += 16) {
            #pragma unroll
            for (int u = 0; u < 16; ++u)
                a[u] = fmaf(zx[j0 + i + u], Wp[(size_t)(i + u) * H2_], a[u]);
        }
    }
    float acc = 0.0f;
    #pragma unroll
    for (int u = 0; u < 16; ++u) acc += a[u];

    __shared__ float part[8][32];
    part[kc][hl] = acc;
    __syncthreads();
    if (kc == 0) {
        float r = b_c[h];
        #pragma unroll
        for (int c = 0; c < 8; ++c) r += part[c][hl];
        combined[b * H2_ + h] = r;
    }
}

// Kernel 2: e[row] = sum_h tanh(enc[row][h] + cov[row]*W_c[h] + combined[b][h]) * v[h]
// Wave-per-row (proven structure). MLP fix: issue all 4 enc (HBM) loads
// back-to-back FIRST, then the 12 L2-hot loads, then compute -- keeps 4
// long-latency loads in flight per thread (round-7 trace showed 28 VGPR,
// i.e. ~1-2 in flight, ~5.9 of 7.1 TB/s achievable).
// block = 256 = 4 waves = 4 rows, grid = B*S/4 = 8192, (256,4).
__global__ __launch_bounds__(256, 4) void et_kernel(
    const float* __restrict__ enc,       // [B, S, H2]
    const float* __restrict__ coverage,  // [B, S]
    const float* __restrict__ W_c,       // [H2]
    const float* __restrict__ v,         // [H2]
    const float* __restrict__ combined,  // [B, H2]
    float* __restrict__ e_out)           // [B, S]
{
    const int tid  = threadIdx.x;
    const int row  = blockIdx.x * 4 + (tid >> 6);   // 4 rows per block
    const int b    = row >> 10;                     // S = 1024
    const int lane = tid & 63;

    const f4* e4   = (const f4*)enc + (size_t)row * (H2_ / 4);
    const f4* com4 = (const f4*)(combined + (size_t)b * H2_);
    const f4* wc4  = (const f4*)W_c;
    const f4* v4   = (const f4*)v;

    const float cov = coverage[row];

    // 1) HBM stream: all 4 enc loads issued consecutively (16 VGPR dest).
    f4 e[4];
    #pragma unroll
    for (int i = 0; i < 4; ++i) e[i] = e4[lane + i * 64];

    // 2) L2/L3-hot streams.
    f4 w[4], vv[4], cb[4];
    #pragma unroll
    for (int i = 0; i < 4; ++i) {
        const int idx = lane + i * 64;
        w[i]  = wc4[idx];
        vv[i] = v4[idx];
        cb[i] = com4[idx];
    }

    // 3) Compute (first use of e[] is here -> waitcnt sits after all issues).
    float acc = 0.0f;
    #pragma unroll
    for (int i = 0; i < 4; ++i) {
        acc = fmaf(fast_tanh(fmaf(cov, w[i].x, e[i].x) + cb[i].x), vv[i].x, acc);
        acc = fmaf(fast_tanh(fmaf(cov, w[i].y, e[i].y) + cb[i].y), vv[i].y, acc);
        acc = fmaf(fast_tanh(fmaf(cov, w[i].z, e[i].z) + cb[i].z), vv[i].z, acc);
        acc = fmaf(fast_tanh(fmaf(cov, w[i].w, e[i].w) + cb[i].w), vv[i].w, acc);
    }

    #pragma unroll
    for (int off = 32; off > 0; off >>= 1)
        acc += __shfl_xor(acc, off, 64);

    if (lane == 0)
        e_out[row] = acc;
}

// Kernel 3: masked softmax over S per batch + next_coverage.
// Single-pass (no max subtraction): |e| <= ||v||_1 ~ 26 since |tanh|<=1,
// so exp(e) is finite-safe in fp32; masked lanes contribute exactly 0.
// Vectorized f4/int4 loads and f4 stores.
// grid = B, block = 256 (4 elems per thread)
__global__ __launch_bounds__(256) void softmax_kernel(
    const float* __restrict__ e_in,      // [B, S]
    const int*   __restrict__ mask,      // [B, S]
    const float* __restrict__ coverage,  // [B, S]
    float* __restrict__ a_out,           // [B, S]
    float* __restrict__ cov_out)         // [B, S]
{
    const int b   = blockIdx.x;
    const int tid = threadIdx.x;

    const f4  ev = ((const f4*)(e_in + b * S_))[tid];
    const int4 mk = ((const int4*)(mask + b * S_))[tid];
    const f4  cv = ((const f4*)(coverage + b * S_))[tid];

    f4 p;
    p.x = (mk.x == 0) ? 0.0f : __expf(ev.x);
    p.y = (mk.y == 0) ? 0.0f : __expf(ev.y);
    p.z = (mk.z == 0) ? 0.0f : __expf(ev.z);
    p.w = (mk.w == 0) ? 0.0f : __expf(ev.w);

    float lsum = (p.x + p.y) + (p.z + p.w);
    #pragma unroll
    for (int off = 1; off < 64; off <<= 1)
        lsum += __shfl_xor(lsum, off, 64);

    __shared__ float red[4];
    if ((tid & 63) == 0) red[tid >> 6] = lsum;
    __syncthreads();
    const float tot = red[0] + red[1] + red[2] + red[3];
    const float inv = 1.0f / tot;

    f4 a, nc;
    a.x = p.x * inv;  a.y = p.y * inv;  a.z = p.z * inv;  a.w = p.w * inv;
    nc.x = cv.x + a.x; nc.y = cv.y + a.y; nc.z = cv.z + a.z; nc.w = cv.w + a.w;

    ((f4*)(a_out   + b * S_))[tid] = a;
    ((f4*)(cov_out + b * S_))[tid] = nc;
}

extern "C" void kernel_launch(void* const* d_in, const int* in_sizes, int n_in,
                              void* d_out, int out_size, void* d_ws, size_t ws_size,
                              hipStream_t stream) {
    const float* enc      = (const float*)d_in[0];
    const int*   mask     = (const int*)  d_in[1];
    const float* s        = (const float*)d_in[2];
    const float* coverage = (const float*)d_in[3];
    const float* hz       = (const float*)d_in[4];
    const float* W_s      = (const float*)d_in[5];
    const float* W_c      = (const float*)d_in[6];
    const float* b_c      = (const float*)d_in[7];
    const float* W_z      = (const float*)d_in[8];
    const float* v        = (const float*)d_in[9];

    float* out_a   = (float*)d_out;            // [B, S]
    float* out_cov = out_a + B_ * S_;          // [B, S]

    float* combined = (float*)d_ws;            // [B, H2]
    float* e_ws     = combined + B_ * H2_;     // [B, S]

    combined_kernel<<<dim3(H2_ / 32, B_), 256, 0, stream>>>(s, hz, W_s, W_z, b_c, combined);
    et_kernel<<<(B_ * S_) / 4, 256, 0, stream>>>(enc, coverage, W_c, v, combined, e_ws);
    softmax_kernel<<<B_, 256, 0, stream>>>(e_ws, mask, coverage, out_a, out_cov);
}

// Round 14
// 37.692 us; speedup vs baseline: 1.0135x; 1.0135x over previous
//
#include <hip/hip_runtime.h>
#include <math.h>

#define B_     32
#define S_     1024
#define H2_    1024
#define TOPIC_ 256

typedef float f4 __attribute__((ext_vector_type(4)));

__device__ __forceinline__ float fast_tanh(float x) {
    // tanh(x) = 1 - 2/(exp(2x)+1); saturates to +-1 at extremes.
    float e = __expf(2.0f * x);
    return 1.0f - 2.0f / (e + 1.0f);
}

// Kernel 1: combined[b][h] = sum_k s[b][k]*W_s[k][h] + sum_j hz[b][j]*W_z[j][h] + b_c[h]
// grid = (H2/32, B) = (32, 32), block = 256 (8 k-chunks x 32 h).
// 16 independent accumulators: 160 loads/thread -> 10 dependent load rounds.
__global__ __launch_bounds__(256) void combined_kernel(
    const float* __restrict__ s,    // [B, H2]
    const float* __restrict__ hz,   // [B, TOPIC]
    const float* __restrict__ W_s,  // [H2, H2]  (in, out)
    const float* __restrict__ W_z,  // [TOPIC, H2]
    const float* __restrict__ b_c,  // [H2]
    float* __restrict__ combined)   // [B, H2]
{
    const int b  = blockIdx.y;
    const int hl = threadIdx.x & 31;
    const int h  = blockIdx.x * 32 + hl;
    const int kc = threadIdx.x >> 5;   // 0..7

    __shared__ float sx[H2_];
    __shared__ float zx[TOPIC_];
    for (int i = threadIdx.x; i < H2_; i += 256)    sx[i] = s[b * H2_ + i];
    for (int i = threadIdx.x; i < TOPIC_; i += 256) zx[i] = hz[b * TOPIC_ + i];
    __syncthreads();

    float a[16];
    #pragma unroll
    for (int u = 0; u < 16; ++u) a[u] = 0.0f;
    {
        const int k0 = kc * 128;                       // 1024 / 8
        const float* Wp = W_s + (size_t)k0 * H2_ + h;
        #pragma unroll
        for (int i = 0; i < 128; i += 16) {
            #pragma unroll
            for (int u = 0; u < 16; ++u)
                a[u] = fmaf(sx[k0 + i + u], Wp[(size_t)(i + u) * H2_], a[u]);
        }
    }
    {
        const int j0 = kc * 32;                        // 256 / 8
        const float* Wp = W_z + (size_t)j0 * H2_ + h;
        #pragma unroll
        for (int i = 0; i < 32; i += 16) {
            #pragma unroll
            for (int u = 0; u < 16; ++u)
                a[u] = fmaf(zx[j0 + i + u], Wp[(size_t)(i + u) * H2_], a[u]);
        }
    }
    float acc = 0.0f;
    #pragma unroll
    for (int u = 0; u < 16; ++u) acc += a[u];

    __shared__ float part[8][32];
    part[kc][hl] = acc;
    __syncthreads();
    if (kc == 0) {
        float r = b_c[h];
        #pragma unroll
        for (int c = 0; c < 8; ++c) r += part[c][hl];
        combined[b * H2_ + h] = r;
    }
}

// Kernel 2: e[row] = sum_h tanh(enc[row][h] + cov[row]*W_c[h] + combined[b][h]) * v[h]
// Wave-per-row, round-12 measured-best body (interleaved loads; compiler's
// own scheduling beat explicit load-batching in the r13 A/B).
// block = 256 = 4 waves = 4 rows, grid = B*S/4 = 8192, (256,4) -> 128-VGPR
// budget keeps the float4 loads in flight. Hot operands (wc/v/cb) NOT
// hoisted: L1 sustains them; every reuse-hoist attempt (r6/r8/r9) regressed.
__global__ __launch_bounds__(256, 4) void et_kernel(
    const float* __restrict__ enc,       // [B, S, H2]
    const float* __restrict__ coverage,  // [B, S]
    const float* __restrict__ W_c,       // [H2]
    const float* __restrict__ v,         // [H2]
    const float* __restrict__ combined,  // [B, H2]
    float* __restrict__ e_out)           // [B, S]
{
    const int tid  = threadIdx.x;
    const int row  = blockIdx.x * 4 + (tid >> 6);   // 4 rows per block
    const int b    = row >> 10;                     // S = 1024
    const int lane = tid & 63;

    const f4* e4   = (const f4*)enc + (size_t)row * (H2_ / 4);
    const f4* com4 = (const f4*)(combined + (size_t)b * H2_);
    const f4* wc4  = (const f4*)W_c;
    const f4* v4   = (const f4*)v;

    const float cov = coverage[row];

    float acc = 0.0f;
    #pragma unroll
    for (int i = 0; i < 4; ++i) {
        const int idx = lane + i * 64;              // float4 index within row
        const f4 e  = e4[idx];
        const f4 w  = wc4[idx];
        const f4 vv = v4[idx];
        const f4 cb = com4[idx];
        acc = fmaf(fast_tanh(fmaf(cov, w.x, e.x) + cb.x), vv.x, acc);
        acc = fmaf(fast_tanh(fmaf(cov, w.y, e.y) + cb.y), vv.y, acc);
        acc = fmaf(fast_tanh(fmaf(cov, w.z, e.z) + cb.z), vv.z, acc);
        acc = fmaf(fast_tanh(fmaf(cov, w.w, e.w) + cb.w), vv.w, acc);
    }

    #pragma unroll
    for (int off = 32; off > 0; off >>= 1)
        acc += __shfl_xor(acc, off, 64);

    if (lane == 0)
        e_out[row] = acc;
}

// Kernel 3: masked softmax over S per batch + next_coverage.
// Single-pass (no max subtraction): |e| <= ||v||_1 ~ 26 since |tanh|<=1,
// so exp(e) is finite-safe in fp32; masked lanes contribute exactly 0.
// Vectorized f4/int4 loads and f4 stores.
// grid = B, block = 256 (4 elems per thread)
__global__ __launch_bounds__(256) void softmax_kernel(
    const float* __restrict__ e_in,      // [B, S]
    const int*   __restrict__ mask,      // [B, S]
    const float* __restrict__ coverage,  // [B, S]
    float* __restrict__ a_out,           // [B, S]
    float* __restrict__ cov_out)         // [B, S]
{
    const int b   = blockIdx.x;
    const int tid = threadIdx.x;

    const f4  ev = ((const f4*)(e_in + b * S_))[tid];
    const int4 mk = ((const int4*)(mask + b * S_))[tid];
    const f4  cv = ((const f4*)(coverage + b * S_))[tid];

    f4 p;
    p.x = (mk.x == 0) ? 0.0f : __expf(ev.x);
    p.y = (mk.y == 0) ? 0.0f : __expf(ev.y);
    p.z = (mk.z == 0) ? 0.0f : __expf(ev.z);
    p.w = (mk.w == 0) ? 0.0f : __expf(ev.w);

    float lsum = (p.x + p.y) + (p.z + p.w);
    #pragma unroll
    for (int off = 1; off < 64; off <<= 1)
        lsum += __shfl_xor(lsum, off, 64);

    __shared__ float red[4];
    if ((tid & 63) == 0) red[tid >> 6] = lsum;
    __syncthreads();
    const float tot = red[0] + red[1] + red[2] + red[3];
    const float inv = 1.0f / tot;

    f4 a, nc;
    a.x = p.x * inv;  a.y = p.y * inv;  a.z = p.z * inv;  a.w = p.w * inv;
    nc.x = cv.x + a.x; nc.y = cv.y + a.y; nc.z = cv.z + a.z; nc.w = cv.w + a.w;

    ((f4*)(a_out   + b * S_))[tid] = a;
    ((f4*)(cov_out + b * S_))[tid] = nc;
}

extern "C" void kernel_launch(void* const* d_in, const int* in_sizes, int n_in,
                              void* d_out, int out_size, void* d_ws, size_t ws_size,
                              hipStream_t stream) {
    const float* enc      = (const float*)d_in[0];
    const int*   mask     = (const int*)  d_in[1];
    const float* s        = (const float*)d_in[2];
    const float* coverage = (const float*)d_in[3];
    const float* hz       = (const float*)d_in[4];
    const float* W_s      = (const float*)d_in[5];
    const float* W_c      = (const float*)d_in[6];
    const float* b_c      = (const float*)d_in[7];
    const float* W_z      = (const float*)d_in[8];
    const float* v        = (const float*)d_in[9];

    float* out_a   = (float*)d_out;            // [B, S]
    float* out_cov = out_a + B_ * S_;          // [B, S]

    float* combined = (float*)d_ws;            // [B, H2]
    float* e_ws     = combined + B_ * H2_;     // [B, S]

    combined_kernel<<<dim3(H2_ / 32, B_), 256, 0, stream>>>(s, hz, W_s, W_z, b_c, combined);
    et_kernel<<<(B_ * S_) / 4, 256, 0, stream>>>(enc, coverage, W_c, v, combined, e_ws);
    softmax_kernel<<<B_, 256, 0, stream>>>(e_ws, mask, coverage, out_a, out_cov);
}